// Round 8
// baseline (261.763 us; speedup 1.0000x reference)
//
#include <hip/hip_runtime.h>
#include <hip/hip_fp16.h>

// Circuit: 4-layer sum-product network, real semiring.
// L0: prod (binary fan-in) over virtual input x = [0, 1, pos0, neg0, ...]
// L1: segment-sum (sorted ix_out), 8M edges -> 1M segs
// L2: prod (binary fan-in)
// L3: segment-sum (sorted ix_out), 1M edges -> 125k segs
//
// R8 = R7 with compile fix: __builtin_nontemporal_* requires clang
// ext_vector_type, not HIP_vector_type (float4/uint4 classes).
//
// R7 theory: L0 ~160us because its 4MB fp16 table is NOT actually
// L2-resident -- 128MB of index stream + 8MB stores thrash the same per-XCD
// L2. Fix: persistent grid + window-outer convoy over the table with 2MB
// windows (leaves half of L2 for streams), 16 idx in regs, multiplicative
// accumulators, nt streams. L1 windows also shrunk to 2MB (4 windows).

#define PERS_BLOCKS 2048
#define PERS_THREADS 256
#define WBITS_H 20     // 1M halfs = 2MB window

typedef __attribute__((ext_vector_type(4))) int   iv4;
typedef __attribute__((ext_vector_type(4))) float fv4;
typedef __attribute__((ext_vector_type(4))) unsigned int uv4;

__device__ __forceinline__ iv4 nt_load4(const int* p) {
    return __builtin_nontemporal_load((const iv4*)p);
}

// ---------- convert x_pos f32 -> fp16 table ----------
__global__ void cvt16_kernel(const float* __restrict__ in,
                             uint2* __restrict__ out, int n4) {
    int t = blockIdx.x * blockDim.x + threadIdx.x;
    if (t >= n4) return;
    fv4 f = __builtin_nontemporal_load((const fv4*)(in + 4 * (size_t)t));
    __half2 lo = __floats2half2_rn(f.x, f.y);
    __half2 hi = __floats2half2_rn(f.z, f.w);
    uint2 r;
    r.x = *(const unsigned int*)&lo;
    r.y = *(const unsigned int*)&hi;
    out[t] = r;
}

// ---------- L0: product layer, window-outer convoy over fp16 table --------
__device__ __forceinline__ void mul_factor16(const __half* __restrict__ xp,
                                             int idx, int w, float& acc) {
    if (idx < 2) {
        if (w == 0) acc *= (float)idx;        // constants folded in window 0
    } else {
        int k = (idx - 2) >> 1;
        if ((k >> WBITS_H) == w) {
            float v = __half2float(xp[k]);
            acc *= (idx & 1) ? 1.0f - v : v;
        }
    }
}

template<int NWIN>
__global__ __launch_bounds__(PERS_THREADS)
void prod8_win_kernel(const __half* __restrict__ x16,
                      const int* __restrict__ ix,     // 16 ints per thread
                      unsigned int* __restrict__ out16, // 8 halfs per thread
                      int nT) {
    int t = blockIdx.x * blockDim.x + threadIdx.x;
    bool act = (t < nT);
    iv4 p0, p1, p2, p3;
    if (act) {
        p0 = nt_load4(ix + 16 * (size_t)t);
        p1 = nt_load4(ix + 16 * (size_t)t + 4);
        p2 = nt_load4(ix + 16 * (size_t)t + 8);
        p3 = nt_load4(ix + 16 * (size_t)t + 12);
    } else {
        p0 = p1 = p2 = p3 = (iv4){0, 0, 0, 0};
    }
    float a0 = 1.f, a1 = 1.f, a2 = 1.f, a3 = 1.f;
    float a4 = 1.f, a5 = 1.f, a6 = 1.f, a7 = 1.f;

    #pragma unroll
    for (int w = 0; w < NWIN; ++w) {
        mul_factor16(x16, p0.x, w, a0); mul_factor16(x16, p0.y, w, a0);
        mul_factor16(x16, p0.z, w, a1); mul_factor16(x16, p0.w, w, a1);
        mul_factor16(x16, p1.x, w, a2); mul_factor16(x16, p1.y, w, a2);
        mul_factor16(x16, p1.z, w, a3); mul_factor16(x16, p1.w, w, a3);
        mul_factor16(x16, p2.x, w, a4); mul_factor16(x16, p2.y, w, a4);
        mul_factor16(x16, p2.z, w, a5); mul_factor16(x16, p2.w, w, a5);
        mul_factor16(x16, p3.x, w, a6); mul_factor16(x16, p3.y, w, a6);
        mul_factor16(x16, p3.z, w, a7); mul_factor16(x16, p3.w, w, a7);
    }

    if (act) {
        __half2 h0 = __floats2half2_rn(a0, a1);
        __half2 h1 = __floats2half2_rn(a2, a3);
        __half2 h2 = __floats2half2_rn(a4, a5);
        __half2 h3 = __floats2half2_rn(a6, a7);
        uv4 r;
        r.x = *(const unsigned int*)&h0;
        r.y = *(const unsigned int*)&h1;
        r.z = *(const unsigned int*)&h2;
        r.w = *(const unsigned int*)&h3;
        __builtin_nontemporal_store(r, (uv4*)(out16 + 4 * (size_t)t));
    }
}

// ---------- sum layer over fp16 source, window-outer convoy ----------
template<int NS, int NWIN>
__global__ __launch_bounds__(PERS_THREADS)
void sum_win_h_kernel(const __half* __restrict__ vin,
                      const int* __restrict__ ix_in,
                      const int* __restrict__ ix_out,
                      float* __restrict__ out, int nT4) {
    const int nTh  = gridDim.x * blockDim.x;
    const int gtid = blockIdx.x * blockDim.x + threadIdx.x;
    const int lane = threadIdx.x & 63;

    iv4    a[NS];
    iv4    sg[NS];
    float4 v[NS];
    bool   act[NS];
    #pragma unroll
    for (int s = 0; s < NS; ++s) {
        int t = s * nTh + gtid;
        act[s] = (t < nT4);
        if (act[s]) {
            a[s]  = nt_load4(ix_in  + 4 * (size_t)t);
            sg[s] = nt_load4(ix_out + 4 * (size_t)t);
        } else {
            a[s]  = (iv4){-1, -1, -1, -1};
            sg[s] = (iv4){-1, -1, -1, -1};
        }
        v[s] = make_float4(0.f, 0.f, 0.f, 0.f);
    }

    // one sweep per 2MB window; resident slice + stream share L2
    #pragma unroll
    for (int w = 0; w < NWIN; ++w) {
        #pragma unroll
        for (int s = 0; s < NS; ++s) {
            if ((a[s].x >> WBITS_H) == w) v[s].x = __half2float(vin[a[s].x]);
            if ((a[s].y >> WBITS_H) == w) v[s].y = __half2float(vin[a[s].y]);
            if ((a[s].z >> WBITS_H) == w) v[s].z = __half2float(vin[a[s].z]);
            if ((a[s].w >> WBITS_H) == w) v[s].w = __half2float(vin[a[s].w]);
        }
    }

    #pragma unroll
    for (int s = 0; s < NS; ++s) {
        int seg = -1; float val = 0.f;
        if (act[s]) {
            int cur = sg[s].x; float acc = v[s].x;
            if (sg[s].y == cur) acc += v[s].y; else { atomicAdd(&out[cur], acc); cur = sg[s].y; acc = v[s].y; }
            if (sg[s].z == cur) acc += v[s].z; else { atomicAdd(&out[cur], acc); cur = sg[s].z; acc = v[s].z; }
            if (sg[s].w == cur) acc += v[s].w; else { atomicAdd(&out[cur], acc); cur = sg[s].w; acc = v[s].w; }
            seg = cur; val = acc;
        }
        #pragma unroll
        for (int off = 1; off < 64; off <<= 1) {
            float vv = __shfl_up(val, off, 64);
            int   ss = __shfl_up(seg, off, 64);
            if (lane >= off && ss == seg) val += vv;
        }
        int seg_next = __shfl_down(seg, 1, 64);
        bool is_last = (lane == 63) || (seg_next != seg);
        if (act[s] && is_last) atomicAdd(&out[seg], val);
    }
}

// ---------- sum layer over f32 source, single pass (small) ----------
__global__ void sum4_f32_kernel(const float* __restrict__ vin,
                                const int* __restrict__ ix_in,
                                const int* __restrict__ ix_out,
                                float* __restrict__ out, int nT4) {
    int t = blockIdx.x * blockDim.x + threadIdx.x;
    int lane = threadIdx.x & 63;
    int seg = -1; float val = 0.f;
    if (t < nT4) {
        iv4 a  = nt_load4(ix_in  + 4 * (size_t)t);
        iv4 sg = nt_load4(ix_out + 4 * (size_t)t);
        float v0 = vin[a.x], v1 = vin[a.y], v2 = vin[a.z], v3 = vin[a.w];
        int cur = sg.x; float acc = v0;
        if (sg.y == cur) acc += v1; else { atomicAdd(&out[cur], acc); cur = sg.y; acc = v1; }
        if (sg.z == cur) acc += v2; else { atomicAdd(&out[cur], acc); cur = sg.z; acc = v2; }
        if (sg.w == cur) acc += v3; else { atomicAdd(&out[cur], acc); cur = sg.w; acc = v3; }
        seg = cur; val = acc;
    }
    #pragma unroll
    for (int off = 1; off < 64; off <<= 1) {
        float vv = __shfl_up(val, off, 64);
        int   ss = __shfl_up(seg, off, 64);
        if (lane >= off && ss == seg) val += vv;
    }
    int seg_next = __shfl_down(seg, 1, 64);
    bool is_last = (lane == 63) || (seg_next != seg);
    if (t < nT4 && is_last) atomicAdd(&out[seg], val);
}

// ---------- L2: small product layer ----------
__global__ void prod2_kernel(const float* __restrict__ vin,
                             const int* __restrict__ ix,
                             float2* __restrict__ out, int nT) {
    int t = blockIdx.x * blockDim.x + threadIdx.x;
    if (t >= nT) return;
    iv4 p = nt_load4(ix + 4 * (size_t)t);
    float a0 = vin[p.x], b0 = vin[p.y];
    float a1 = vin[p.z], b1 = vin[p.w];
    float2 r; r.x = a0 * b0; r.y = a1 * b1;
    out[t] = r;
}

extern "C" void kernel_launch(void* const* d_in, const int* in_sizes, int n_in,
                              void* d_out, int out_size, void* d_ws, size_t ws_size,
                              hipStream_t stream) {
    const float* x_pos  = (const float*)d_in[0];
    const int*   ix_in0 = (const int*)d_in[1];
    const int*   ix_in1 = (const int*)d_in[2];
    const int*   ix_out1= (const int*)d_in[3];
    const int*   ix_in2 = (const int*)d_in[4];
    const int*   ix_in3 = (const int*)d_in[5];
    const int*   ix_out3= (const int*)d_in[6];
    float* out = (float*)d_out;

    const int NV = in_sizes[0];       // 2,000,000
    const int M0 = in_sizes[1] / 2;   // 4,000,000
    const int E1 = in_sizes[2];       // 8,000,000
    const int M1 = 1000000;
    const int M2 = in_sizes[4] / 2;   // 500,000
    const int E3 = in_sizes[5];       // 1,000,000
    const int M3 = out_size;          // 125,000

    char* ws = (char*)d_ws;
    __half* y0  = (__half*)(ws);                            //  8 MB
    float*  y1  = (float*)(ws + (size_t)8  * 1024 * 1024);  //  4 MB
    float*  y2  = (float*)(ws + (size_t)12 * 1024 * 1024);  //  2 MB
    __half* x16 = (__half*)(ws + (size_t)14 * 1024 * 1024); //  4 MB

    hipError_t e0 = hipMemsetAsync(y1,  0, (size_t)M1 * sizeof(float), stream); (void)e0;
    hipError_t e1 = hipMemsetAsync(out, 0, (size_t)M3 * sizeof(float), stream); (void)e1;

    const int B = 256;

    // convert x_pos -> fp16 table (4MB)
    int nc = NV / 4;
    cvt16_kernel<<<(nc + B - 1) / B, B, 0, stream>>>(
        x_pos, (uint2*)x16, nc);

    // L0: 500K threads x 8 products; convoy over 2 x 2MB windows of x16
    int t0 = M0 / 8;
    prod8_win_kernel<2><<<PERS_BLOCKS, PERS_THREADS, 0, stream>>>(
        x16, ix_in0, (unsigned int*)y0, t0);

    // L1: fp16 source 8MB -> 4 x 2MB windows, convoy, NS=4 covers 2M slots
    int t1 = E1 / 4;
    sum_win_h_kernel<4, 4><<<PERS_BLOCKS, PERS_THREADS, 0, stream>>>(
        y0, ix_in1, ix_out1, y1, t1);

    // L2: y1 f32 4MB
    int t2 = M2 / 2;
    prod2_kernel<<<(t2 + B - 1) / B, B, 0, stream>>>(
        y1, ix_in2, (float2*)y2, t2);

    // L3: y2 f32 2MB, single pass
    int t3 = E3 / 4;
    sum4_f32_kernel<<<(t3 + B - 1) / B, B, 0, stream>>>(
        y2, ix_in3, ix_out3, out, t3);
}

// Round 9
// 252.645 us; speedup vs baseline: 1.0361x; 1.0361x over previous
//
#include <hip/hip_runtime.h>
#include <hip/hip_fp16.h>

// Circuit: 4-layer sum-product network, real semiring.
// L0: prod (binary fan-in) over virtual input x = [0, 1, pos0, neg0, ...]
// L1: segment-sum (sorted ix_out), 8M edges -> 1M segs
// L2: prod (binary fan-in)
// L3: segment-sum (sorted ix_out), 1M edges -> 125k segs
//
// R9: dispatch-count reduction (7 -> 5). Accounting across R1-R8 leaves
// ~90us unexplained vs visible kernel time with 7-8 dispatches -> test
// per-dispatch overhead theory: fold both memsets into the cvt kernel.
// L0 reverted to straight (unwindowed) prod8 — R8's windowed L0 cost VALU
// for no byte win. L1 kernel unchanged from R8 (72us, FETCH 87MB,
// request-path bound).

#define PERS_BLOCKS 2048
#define PERS_THREADS 256
#define WBITS_H 20     // 1M halfs = 2MB window

typedef __attribute__((ext_vector_type(4))) int   iv4;
typedef __attribute__((ext_vector_type(4))) float fv4;
typedef __attribute__((ext_vector_type(4))) unsigned int uv4;

__device__ __forceinline__ iv4 nt_load4(const int* p) {
    return __builtin_nontemporal_load((const iv4*)p);
}

// ---------- init: cvt x_pos f32 -> fp16 table, zero y1 and out ----------
__global__ void init_kernel(const float* __restrict__ in, unsigned int* __restrict__ x16,
                            float* __restrict__ y1, float* __restrict__ out,
                            int n4, int nz1, int nzo) {
    int t = blockIdx.x * blockDim.x + threadIdx.x;
    if (t < n4) {
        fv4 f = __builtin_nontemporal_load((const fv4*)(in + 4 * (size_t)t));
        __half2 lo = __floats2half2_rn(f.x, f.y);
        __half2 hi = __floats2half2_rn(f.z, f.w);
        unsigned int rlo = *(const unsigned int*)&lo;
        unsigned int rhi = *(const unsigned int*)&hi;
        x16[2 * t]     = rlo;
        x16[2 * t + 1] = rhi;
    }
    if (t < nz1) {   // zero y1: nz1 float4 stores
        fv4 z = {0.f, 0.f, 0.f, 0.f};
        __builtin_nontemporal_store(z, (fv4*)(y1 + 4 * (size_t)t));
    }
    if (t < nzo) {   // zero out: nzo float4 stores
        fv4 z = {0.f, 0.f, 0.f, 0.f};
        __builtin_nontemporal_store(z, (fv4*)(out + 4 * (size_t)t));
    }
}

// ---------- L0: 8 products/thread, straight gathers from fp16 table -------
__device__ __forceinline__ float decode16(const __half* __restrict__ xp, int idx) {
    int k = (idx - 2) >> 1;
    k = k < 0 ? 0 : k;                 // safe unconditional load (ILP)
    float v = __half2float(xp[k]);
    v = (idx & 1) ? 1.0f - v : v;
    if (idx < 2) v = (float)idx;       // constants override
    return v;
}

__global__ void layer0_prod8_kernel(const __half* __restrict__ x16,
                                    const int* __restrict__ ix,
                                    unsigned int* __restrict__ out16, int nT) {
    int t = blockIdx.x * blockDim.x + threadIdx.x;
    if (t >= nT) return;
    iv4 p0 = nt_load4(ix + 16 * (size_t)t);
    iv4 p1 = nt_load4(ix + 16 * (size_t)t + 4);
    iv4 p2 = nt_load4(ix + 16 * (size_t)t + 8);
    iv4 p3 = nt_load4(ix + 16 * (size_t)t + 12);
    float a0 = decode16(x16, p0.x), b0 = decode16(x16, p0.y);
    float a1 = decode16(x16, p0.z), b1 = decode16(x16, p0.w);
    float a2 = decode16(x16, p1.x), b2 = decode16(x16, p1.y);
    float a3 = decode16(x16, p1.z), b3 = decode16(x16, p1.w);
    float a4 = decode16(x16, p2.x), b4 = decode16(x16, p2.y);
    float a5 = decode16(x16, p2.z), b5 = decode16(x16, p2.w);
    float a6 = decode16(x16, p3.x), b6 = decode16(x16, p3.y);
    float a7 = decode16(x16, p3.z), b7 = decode16(x16, p3.w);
    __half2 h0 = __floats2half2_rn(a0 * b0, a1 * b1);
    __half2 h1 = __floats2half2_rn(a2 * b2, a3 * b3);
    __half2 h2 = __floats2half2_rn(a4 * b4, a5 * b5);
    __half2 h3 = __floats2half2_rn(a6 * b6, a7 * b7);
    uv4 r;
    r.x = *(const unsigned int*)&h0;
    r.y = *(const unsigned int*)&h1;
    r.z = *(const unsigned int*)&h2;
    r.w = *(const unsigned int*)&h3;
    __builtin_nontemporal_store(r, (uv4*)(out16 + 4 * (size_t)t));
}

// ---------- L1: sum over fp16 source, window-outer convoy (unchanged) -----
template<int NS, int NWIN>
__global__ __launch_bounds__(PERS_THREADS)
void sum_win_h_kernel(const __half* __restrict__ vin,
                      const int* __restrict__ ix_in,
                      const int* __restrict__ ix_out,
                      float* __restrict__ out, int nT4) {
    const int nTh  = gridDim.x * blockDim.x;
    const int gtid = blockIdx.x * blockDim.x + threadIdx.x;
    const int lane = threadIdx.x & 63;

    iv4    a[NS];
    iv4    sg[NS];
    float4 v[NS];
    bool   act[NS];
    #pragma unroll
    for (int s = 0; s < NS; ++s) {
        int t = s * nTh + gtid;
        act[s] = (t < nT4);
        if (act[s]) {
            a[s]  = nt_load4(ix_in  + 4 * (size_t)t);
            sg[s] = nt_load4(ix_out + 4 * (size_t)t);
        } else {
            a[s]  = (iv4){-1, -1, -1, -1};
            sg[s] = (iv4){-1, -1, -1, -1};
        }
        v[s] = make_float4(0.f, 0.f, 0.f, 0.f);
    }

    #pragma unroll
    for (int w = 0; w < NWIN; ++w) {
        #pragma unroll
        for (int s = 0; s < NS; ++s) {
            if ((a[s].x >> WBITS_H) == w) v[s].x = __half2float(vin[a[s].x]);
            if ((a[s].y >> WBITS_H) == w) v[s].y = __half2float(vin[a[s].y]);
            if ((a[s].z >> WBITS_H) == w) v[s].z = __half2float(vin[a[s].z]);
            if ((a[s].w >> WBITS_H) == w) v[s].w = __half2float(vin[a[s].w]);
        }
    }

    #pragma unroll
    for (int s = 0; s < NS; ++s) {
        int seg = -1; float val = 0.f;
        if (act[s]) {
            int cur = sg[s].x; float acc = v[s].x;
            if (sg[s].y == cur) acc += v[s].y; else { atomicAdd(&out[cur], acc); cur = sg[s].y; acc = v[s].y; }
            if (sg[s].z == cur) acc += v[s].z; else { atomicAdd(&out[cur], acc); cur = sg[s].z; acc = v[s].z; }
            if (sg[s].w == cur) acc += v[s].w; else { atomicAdd(&out[cur], acc); cur = sg[s].w; acc = v[s].w; }
            seg = cur; val = acc;
        }
        #pragma unroll
        for (int off = 1; off < 64; off <<= 1) {
            float vv = __shfl_up(val, off, 64);
            int   ss = __shfl_up(seg, off, 64);
            if (lane >= off && ss == seg) val += vv;
        }
        int seg_next = __shfl_down(seg, 1, 64);
        bool is_last = (lane == 63) || (seg_next != seg);
        if (act[s] && is_last) atomicAdd(&out[seg], val);
    }
}

// ---------- L3: sum over f32 source, single pass (small) ----------
__global__ void sum4_f32_kernel(const float* __restrict__ vin,
                                const int* __restrict__ ix_in,
                                const int* __restrict__ ix_out,
                                float* __restrict__ out, int nT4) {
    int t = blockIdx.x * blockDim.x + threadIdx.x;
    int lane = threadIdx.x & 63;
    int seg = -1; float val = 0.f;
    if (t < nT4) {
        iv4 a  = nt_load4(ix_in  + 4 * (size_t)t);
        iv4 sg = nt_load4(ix_out + 4 * (size_t)t);
        float v0 = vin[a.x], v1 = vin[a.y], v2 = vin[a.z], v3 = vin[a.w];
        int cur = sg.x; float acc = v0;
        if (sg.y == cur) acc += v1; else { atomicAdd(&out[cur], acc); cur = sg.y; acc = v1; }
        if (sg.z == cur) acc += v2; else { atomicAdd(&out[cur], acc); cur = sg.z; acc = v2; }
        if (sg.w == cur) acc += v3; else { atomicAdd(&out[cur], acc); cur = sg.w; acc = v3; }
        seg = cur; val = acc;
    }
    #pragma unroll
    for (int off = 1; off < 64; off <<= 1) {
        float vv = __shfl_up(val, off, 64);
        int   ss = __shfl_up(seg, off, 64);
        if (lane >= off && ss == seg) val += vv;
    }
    int seg_next = __shfl_down(seg, 1, 64);
    bool is_last = (lane == 63) || (seg_next != seg);
    if (t < nT4 && is_last) atomicAdd(&out[seg], val);
}

// ---------- L2: small product layer ----------
__global__ void prod2_kernel(const float* __restrict__ vin,
                             const int* __restrict__ ix,
                             float2* __restrict__ out, int nT) {
    int t = blockIdx.x * blockDim.x + threadIdx.x;
    if (t >= nT) return;
    iv4 p = nt_load4(ix + 4 * (size_t)t);
    float a0 = vin[p.x], b0 = vin[p.y];
    float a1 = vin[p.z], b1 = vin[p.w];
    float2 r; r.x = a0 * b0; r.y = a1 * b1;
    out[t] = r;
}

extern "C" void kernel_launch(void* const* d_in, const int* in_sizes, int n_in,
                              void* d_out, int out_size, void* d_ws, size_t ws_size,
                              hipStream_t stream) {
    const float* x_pos  = (const float*)d_in[0];
    const int*   ix_in0 = (const int*)d_in[1];
    const int*   ix_in1 = (const int*)d_in[2];
    const int*   ix_out1= (const int*)d_in[3];
    const int*   ix_in2 = (const int*)d_in[4];
    const int*   ix_in3 = (const int*)d_in[5];
    const int*   ix_out3= (const int*)d_in[6];
    float* out = (float*)d_out;

    const int NV = in_sizes[0];       // 2,000,000
    const int M0 = in_sizes[1] / 2;   // 4,000,000
    const int E1 = in_sizes[2];       // 8,000,000
    const int M1 = 1000000;
    const int M2 = in_sizes[4] / 2;   // 500,000
    const int E3 = in_sizes[5];       // 1,000,000
    const int M3 = out_size;          // 125,000

    char* ws = (char*)d_ws;
    __half* y0  = (__half*)(ws);                            //  8 MB
    float*  y1  = (float*)(ws + (size_t)8  * 1024 * 1024);  //  4 MB
    float*  y2  = (float*)(ws + (size_t)12 * 1024 * 1024);  //  2 MB
    __half* x16 = (__half*)(ws + (size_t)14 * 1024 * 1024); //  4 MB

    const int B = 256;

    // 1) init: cvt x_pos -> fp16 table + zero y1 + zero out (one dispatch)
    int n4  = NV / 4;          // 500,000 cvt quads
    int nz1 = M1 / 4;          // 250,000 float4 zeros for y1
    int nzo = M3 / 4;          //  31,250 float4 zeros for out
    init_kernel<<<(n4 + B - 1) / B, B, 0, stream>>>(
        x_pos, (unsigned int*)x16, y1, out, n4, nz1, nzo);

    // 2) L0: 500K threads x 8 products, straight gathers from 4MB table
    int t0 = M0 / 8;
    layer0_prod8_kernel<<<(t0 + B - 1) / B, B, 0, stream>>>(
        x16, ix_in0, (unsigned int*)y0, t0);

    // 3) L1: fp16 source 8MB -> 4 x 2MB windows, convoy, NS=4 covers 2M slots
    int t1 = E1 / 4;
    sum_win_h_kernel<4, 4><<<PERS_BLOCKS, PERS_THREADS, 0, stream>>>(
        y0, ix_in1, ix_out1, y1, t1);

    // 4) L2: y1 f32 4MB
    int t2 = M2 / 2;
    prod2_kernel<<<(t2 + B - 1) / B, B, 0, stream>>>(
        y1, ix_in2, (float2*)y2, t2);

    // 5) L3: y2 f32 2MB, single pass
    int t3 = E3 / 4;
    sum4_f32_kernel<<<(t3 + B - 1) / B, B, 0, stream>>>(
        y2, ix_in3, ix_out3, out, t3);
}